// Round 2
// baseline (293.083 us; speedup 1.0000x reference)
//
#include <hip/hip_runtime.h>
#include <math.h>

// Problem constants
#define B_  4
#define C_  256
#define N_  4096
#define CK_ 32
#define CV_ 128

typedef __attribute__((ext_vector_type(8))) short short8;  // 8 bf16 = 4 VGPRs
typedef __attribute__((ext_vector_type(4))) float f32x4;   // MFMA C/D frag
typedef unsigned short u16;
typedef unsigned int   u32;

static constexpr float LOG2E = 1.4426950408889634f;

static __device__ __forceinline__ u16 f2bf(float f) {       // fp32 -> bf16 RNE
    u32 u = __float_as_uint(f);
    u = (u + 0x7FFFu + ((u >> 16) & 1u)) >> 16;
    return (u16)u;
}
static __device__ __forceinline__ float bf2f(u16 h) {
    return __uint_as_float(((u32)h) << 16);
}

// native 2^x (v_exp_f32)
static __device__ __forceinline__ float fexp2(float x) {
#if __has_builtin(__builtin_amdgcn_exp2f)
    return __builtin_amdgcn_exp2f(x);
#else
    float r; asm("v_exp_f32 %0, %1\n\ts_nop 0" : "=v"(r) : "v"(x)); return r;
#endif
}
static __device__ __forceinline__ float frcp(float x) {
#if __has_builtin(__builtin_amdgcn_rcpf)
    return __builtin_amdgcn_rcpf(x);
#else
    float r; asm("v_rcp_f32 %0, %1\n\ts_nop 0" : "=v"(r) : "v"(x)); return r;
#endif
}
// pack two fp32 -> 2x bf16 (RNE), lo = a, hi = b
static __device__ __forceinline__ u32 cvt_pk_bf16(float a, float b) {
    u32 r; asm("v_cvt_pk_bf16_f32 %0, %1, %2" : "=v"(r) : "v"(a), "v"(b));
    return r;
}

// ---------------------------------------------------------------------------
// Kernel 0a: weight convert. W16[192][256] = [theta*log2e; phi; g] bf16,
// ow16[256][128] bf16. 81920 elements, grid 320x256.
// ---------------------------------------------------------------------------
__global__ __launch_bounds__(256) void wconv_kernel(
    const float* __restrict__ theta_w, const float* __restrict__ phi_w,
    const float* __restrict__ g_w,     const float* __restrict__ o_w,
    u16* __restrict__ W16, u16* __restrict__ ow16)
{
    const int idx = blockIdx.x * 256 + threadIdx.x;
    if (idx < 8192)        W16[idx] = f2bf(theta_w[idx] * LOG2E);
    else if (idx < 16384)  W16[idx] = f2bf(phi_w[idx - 8192]);
    else if (idx < 49152)  W16[idx] = f2bf(g_w[idx - 16384]);
    else                   ow16[idx - 49152] = f2bf(o_w[idx - 49152]);
}

// ---------------------------------------------------------------------------
// Kernel 0b: x [B][C][N] fp32 -> xT16 [B][N][C] bf16 (transpose + convert).
// ---------------------------------------------------------------------------
__global__ __launch_bounds__(256) void xt_kernel(
    const float* __restrict__ x, u16* __restrict__ xT16)
{
    const int b = blockIdx.z, c0 = blockIdx.y * 64, n0 = blockIdx.x * 64;
    const int t = threadIdx.x;
    __shared__ float tile[64][65];

    const int cr = t >> 4, nc = (t & 15) * 4;
    #pragma unroll
    for (int it = 0; it < 4; ++it) {
        const float4 v = *(const float4*)(x + (size_t)(b * C_ + c0 + cr + it * 16) * N_ + n0 + nc);
        tile[cr + it * 16][nc + 0] = v.x; tile[cr + it * 16][nc + 1] = v.y;
        tile[cr + it * 16][nc + 2] = v.z; tile[cr + it * 16][nc + 3] = v.w;
    }
    __syncthreads();
    const int n = t >> 2, cg = (t & 3) * 16;
    union { u16 us[16]; uint4 u4[2]; } pk;
    #pragma unroll
    for (int e = 0; e < 16; ++e) pk.us[e] = f2bf(tile[cg + e][n]);
    uint4* dst = (uint4*)(xT16 + (size_t)(b * N_ + n0 + n) * C_ + c0 + cg);
    dst[0] = pk.u4[0]; dst[1] = pk.u4[1];
}

// ---------------------------------------------------------------------------
// Kernel 1: projections via MFMA (unchanged).
// ---------------------------------------------------------------------------
__global__ __launch_bounds__(256) void proj_mfma_kernel(
    const u16* __restrict__ xT16, const u16* __restrict__ W16,
    const float* __restrict__ theta_b, const float* __restrict__ phi_b,
    const float* __restrict__ g_b,
    u16* __restrict__ theta_t, u16* __restrict__ phi_t, u16* __restrict__ g16)
{
    const int b = blockIdx.y, n0 = blockIdx.x * 64;
    const int w = threadIdx.x >> 6, lane = threadIdx.x & 63;
    const int lr = lane & 15, q = lane >> 4;
    const f32x4 zf = {0.f, 0.f, 0.f, 0.f};

    // ---- theta/phi: wave w owns pixel m-tile w ----
    const u16* xrow = xT16 + (size_t)(b * N_ + n0 + w * 16 + lr) * C_;
    f32x4 acc[4];
    #pragma unroll
    for (int nt = 0; nt < 4; ++nt) acc[nt] = zf;
    for (int ks = 0; ks < 8; ++ks) {
        const short8 aX = *(const short8*)(xrow + ks * 32 + q * 8);
        #pragma unroll
        for (int nt = 0; nt < 4; ++nt) {
            const short8 bW = *(const short8*)(W16 + (size_t)(nt * 16 + lr) * C_ + ks * 32 + q * 8);
            acc[nt] = __builtin_amdgcn_mfma_f32_16x16x32_bf16(aX, bW, acc[nt], 0, 0, 0);
        }
    }
    #pragma unroll
    for (int nt = 0; nt < 4; ++nt) {
        const int o = nt * 16 + lr;
        #pragma unroll
        for (int reg = 0; reg < 4; ++reg) {
            const int n = n0 + w * 16 + q * 4 + reg;
            if (nt < 2)
                theta_t[(size_t)(b * N_ + n) * CK_ + o] = f2bf(acc[nt][reg] + theta_b[o] * LOG2E);
            else
                phi_t[(size_t)(b * N_ + n) * CK_ + (o - 32)] = f2bf(acc[nt][reg] + phi_b[o - 32]);
        }
    }

    // ---- g: wave w owns c m-tiles {2w, 2w+1} ----
    #pragma unroll
    for (int mp = 0; mp < 2; ++mp) {
        const int crow = (w * 2 + mp) * 16;
        f32x4 ag[4];
        #pragma unroll
        for (int nt = 0; nt < 4; ++nt) ag[nt] = zf;
        for (int ks = 0; ks < 8; ++ks) {
            const short8 aW = *(const short8*)(W16 + (size_t)(64 + crow + lr) * C_ + ks * 32 + q * 8);
            #pragma unroll
            for (int nt = 0; nt < 4; ++nt) {
                const short8 bX = *(const short8*)(xT16 + (size_t)(b * N_ + n0 + nt * 16 + lr) * C_ + ks * 32 + q * 8);
                ag[nt] = __builtin_amdgcn_mfma_f32_16x16x32_bf16(aW, bX, ag[nt], 0, 0, 0);
            }
        }
        #pragma unroll
        for (int nt = 0; nt < 4; ++nt) {
            #pragma unroll
            for (int reg = 0; reg < 4; ++reg) {
                const int c = crow + q * 4 + reg;
                const int n = n0 + nt * 16 + lr;
                g16[(size_t)(b * CV_ + c) * N_ + n] = f2bf(ag[nt][reg] + g_b[c]);
            }
        }
    }
}

// ---------------------------------------------------------------------------
// Kernel 2: Z[b][j] = sum_i exp2(S[i][j]) via MFMA. Native v_exp_f32.
// ---------------------------------------------------------------------------
__global__ __launch_bounds__(256) void colstats_kernel(
    const u16* __restrict__ theta_t, const u16* __restrict__ phi_t,
    float* __restrict__ Z)
{
    const int b  = blockIdx.z;
    const int j0 = blockIdx.x * 32;
    const int istart = blockIdx.y * (N_ / 4);
    const int tid = threadIdx.x;
    const int wave = tid >> 6, lane = tid & 63;
    const int lr = lane & 15, q = lane >> 4;

    const int jW = j0 + (wave & 1) * 16;
    const short8 bF = *(const short8*)(phi_t + (size_t)(b * N_ + jW + lr) * CK_ + q * 8);

    const u16* thp = theta_t + (size_t)b * N_ * CK_;
    const f32x4 zero = {0.f, 0.f, 0.f, 0.f};
    float zacc = 0.f;
    for (int it = istart + (wave >> 1) * 16; it < istart + N_ / 4; it += 32) {
        const short8 aF = *(const short8*)(thp + (size_t)(it + lr) * CK_ + q * 8);
        f32x4 S = __builtin_amdgcn_mfma_f32_16x16x32_bf16(aF, bF, zero, 0, 0, 0);
        zacc += fexp2(S[0]) + fexp2(S[1]) + fexp2(S[2]) + fexp2(S[3]);
    }
    zacc += __shfl_xor(zacc, 16);
    zacc += __shfl_xor(zacc, 32);
    if (lane < 16) atomicAdd(&Z[(size_t)b * N_ + jW + lr], zacc);
}

// ---------------------------------------------------------------------------
// Kernel 3: fold 1/Z into g (in place, bf16). 8 elems/thread.
// ---------------------------------------------------------------------------
__global__ __launch_bounds__(256) void gscale_kernel(
    u16* __restrict__ g16, const float* __restrict__ Z)
{
    const size_t idx = ((size_t)blockIdx.x * 256 + threadIdx.x) * 8;
    const int n = (int)(idx & (N_ - 1));
    const int b = (int)(idx / ((size_t)CV_ * N_));
    uint4 raw = *(const uint4*)(g16 + idx);
    const float4 z0 = *(const float4*)(Z + (size_t)b * N_ + n);
    const float4 z1 = *(const float4*)(Z + (size_t)b * N_ + n + 4);
    const float zz[8] = {z0.x, z0.y, z0.z, z0.w, z1.x, z1.y, z1.z, z1.w};
    u16* pr = (u16*)&raw;
    union { u16 us[8]; uint4 u4; } pk;
    #pragma unroll
    for (int k = 0; k < 8; ++k) pk.us[k] = f2bf(bf2f(pr[k]) * frcp(zz[k]));
    *(uint4*)(g16 + idx) = pk.u4;
}

// ---------------------------------------------------------------------------
// Kernel 4: o_pre partial = sum_{j in half} gp[c][j] * exp2(S[i][j]).
// BARRIER-FREE, LDS-FREE redesign. The S-MFMA's phi rows are PERMUTED so the
// D-fragment lands exactly in PV's A-fragment layout:
//   Sa uses phi rows j' = (r>>2)*8 + (r&3)   -> lane(lr,q) gets E[i=lr][j=q*8+0..3]
//   Sb uses phi rows j' = (r>>2)*8 + 4+(r&3) -> lane(lr,q) gets E[i=lr][j=q*8+4..7]
// Concatenated via 4x v_cvt_pk_bf16_f32 they form the 16x16x32 A-frag of
//   o_pre^T[i][c] += E(i, j-chunk) x g^T(j-chunk, c)   (B-frag: n=c, k=j).
// Wave = (i-tile 16, c-half 64, j-half, b): 4096 waves, 4/SIMD, no LDS.
// Block = 4 waves sharing (b, jh, ch) with adjacent i-tiles -> phi/g loads
// L1-hit across the block. g/phi prefetched one 32-j chunk ahead in regs.
// ---------------------------------------------------------------------------
__global__ __launch_bounds__(256, 4) void opre_kernel(
    const u16* __restrict__ theta_t, const u16* __restrict__ phi_t,
    const u16* __restrict__ g16, float* __restrict__ o_p0, float* __restrict__ o_p1)
{
    const int bi  = blockIdx.x;
    const int itg = bi & 63, ch = (bi >> 6) & 1, jh = (bi >> 7) & 1, b = bi >> 8;
    const int w = threadIdx.x >> 6, lane = threadIdx.x & 63;
    const int lr = lane & 15, q = lane >> 4;
    const int i0 = (itg * 4 + w) * 16;
    const int c0 = ch * 64;
    const f32x4 zf = {0.f, 0.f, 0.f, 0.f};

    // theta B-frag (n = i), fixed for the wave
    const short8 bT = *(const short8*)(theta_t + (size_t)(b * N_ + i0 + lr) * CK_ + q * 8);

    // phi A-frag row permutation
    const int ja = (lr >> 2) * 8 + (lr & 3);
    const int jstart = jh * (N_ / 2);

    const u16* pA = phi_t + ((size_t)(b * N_) + jstart + ja) * CK_ + q * 8;
    const u16* pG = g16 + (size_t)(b * CV_ + c0 + lr) * N_ + jstart + q * 8;
    const size_t gct = (size_t)16 * N_;

    f32x4 acc[4];
    #pragma unroll
    for (int ct = 0; ct < 4; ++ct) acc[ct] = zf;

    // prefetch chunk 0
    short8 fa0 = *(const short8*)pA;
    short8 fa1 = *(const short8*)(pA + 4 * CK_);
    short8 g0  = *(const short8*)(pG);
    short8 g1  = *(const short8*)(pG + gct);
    short8 g2  = *(const short8*)(pG + 2 * gct);
    short8 g3  = *(const short8*)(pG + 3 * gct);

    #pragma unroll 2
    for (int ckk = 0; ckk < 64; ++ckk) {
        // S^T for this chunk (phi-permuted rows x theta)
        const f32x4 Sa = __builtin_amdgcn_mfma_f32_16x16x32_bf16(fa0, bT, zf, 0, 0, 0);
        const f32x4 Sb = __builtin_amdgcn_mfma_f32_16x16x32_bf16(fa1, bT, zf, 0, 0, 0);

        // prefetch next chunk (adv=0 on last iter: reload same addr, L1 hit)
        const int adv = (ckk < 63) ? 32 : 0;
        pA += (size_t)adv * CK_;  pG += adv;
        const short8 nfa0 = *(const short8*)pA;
        const short8 nfa1 = *(const short8*)(pA + 4 * CK_);
        const short8 ng0  = *(const short8*)(pG);
        const short8 ng1  = *(const short8*)(pG + gct);
        const short8 ng2  = *(const short8*)(pG + 2 * gct);
        const short8 ng3  = *(const short8*)(pG + 3 * gct);

        // E = exp2(S) packed directly into the PV A-fragment
        union { u32 u[4]; short8 s8; } ef;
        ef.u[0] = cvt_pk_bf16(fexp2(Sa[0]), fexp2(Sa[1]));
        ef.u[1] = cvt_pk_bf16(fexp2(Sa[2]), fexp2(Sa[3]));
        ef.u[2] = cvt_pk_bf16(fexp2(Sb[0]), fexp2(Sb[1]));
        ef.u[3] = cvt_pk_bf16(fexp2(Sb[2]), fexp2(Sb[3]));

        // PV: acc[ct] += E x g^T  (D rows = i-local, cols = c-local)
        acc[0] = __builtin_amdgcn_mfma_f32_16x16x32_bf16(ef.s8, g0, acc[0], 0, 0, 0);
        acc[1] = __builtin_amdgcn_mfma_f32_16x16x32_bf16(ef.s8, g1, acc[1], 0, 0, 0);
        acc[2] = __builtin_amdgcn_mfma_f32_16x16x32_bf16(ef.s8, g2, acc[2], 0, 0, 0);
        acc[3] = __builtin_amdgcn_mfma_f32_16x16x32_bf16(ef.s8, g3, acc[3], 0, 0, 0);

        fa0 = nfa0; fa1 = nfa1; g0 = ng0; g1 = ng1; g2 = ng2; g3 = ng3;
    }

    // store fp32 partials: o_p[b][i][c], lane holds [i = q*4+reg][c = ct*16+lr]
    float* op = (jh ? o_p1 : o_p0) + ((size_t)(b * N_) + i0) * CV_ + c0;
    #pragma unroll
    for (int ct = 0; ct < 4; ++ct) {
        #pragma unroll
        for (int reg = 0; reg < 4; ++reg)
            op[(size_t)(q * 4 + reg) * CV_ + ct * 16 + lr] = acc[ct][reg];
    }
}

// ---------------------------------------------------------------------------
// Kernel 5: out = x + gamma * (o_w @ (o_p0 + o_p1) + o_b) via MFMA.
// Grid (N/32, B) = 512 blocks, block 256 (4 waves).
// ---------------------------------------------------------------------------
__global__ __launch_bounds__(256) void final_mfma_kernel(
    const float* __restrict__ o_p0, const float* __restrict__ o_p1,
    const u16* __restrict__ ow16, const float* __restrict__ o_b,
    const float* __restrict__ gamma, const float* __restrict__ x,
    float* __restrict__ out)
{
    const int b = blockIdx.y, n0 = blockIdx.x * 32;
    const int w = threadIdx.x >> 6, lane = threadIdx.x & 63;
    const int lr = lane & 15, q = lane >> 4;
    const f32x4 zf = {0.f, 0.f, 0.f, 0.f};

    f32x4 acc[4][2];
    #pragma unroll
    for (int mt = 0; mt < 4; ++mt)
        #pragma unroll
        for (int nt = 0; nt < 2; ++nt) acc[mt][nt] = zf;

    const float* p0 = o_p0 + (size_t)(b * N_ + n0) * CV_;
    const float* p1 = o_p1 + (size_t)(b * N_ + n0) * CV_;

    for (int ks = 0; ks < 4; ++ks) {
        short8 bP[2];
        #pragma unroll
        for (int nt = 0; nt < 2; ++nt) {
            const size_t base = (size_t)(nt * 16 + lr) * CV_ + ks * 32 + q * 8;
            const float4 a0 = *(const float4*)(p0 + base);
            const float4 a1 = *(const float4*)(p0 + base + 4);
            const float4 c0 = *(const float4*)(p1 + base);
            const float4 c1 = *(const float4*)(p1 + base + 4);
            union { u32 u[4]; short8 s8; } pk;
            pk.u[0] = cvt_pk_bf16(a0.x + c0.x, a0.y + c0.y);
            pk.u[1] = cvt_pk_bf16(a0.z + c0.z, a0.w + c0.w);
            pk.u[2] = cvt_pk_bf16(a1.x + c1.x, a1.y + c1.y);
            pk.u[3] = cvt_pk_bf16(a1.z + c1.z, a1.w + c1.w);
            bP[nt] = pk.s8;
        }
        #pragma unroll
        for (int mt = 0; mt < 4; ++mt) {
            const short8 aW = *(const short8*)(ow16 + (size_t)((w * 4 + mt) * 16 + lr) * CV_ + ks * 32 + q * 8);
            #pragma unroll
            for (int nt = 0; nt < 2; ++nt)
                acc[mt][nt] = __builtin_amdgcn_mfma_f32_16x16x32_bf16(aW, bP[nt], acc[mt][nt], 0, 0, 0);
        }
    }

    const float gm = gamma[0];
    #pragma unroll
    for (int mt = 0; mt < 4; ++mt) {
        #pragma unroll
        for (int nt = 0; nt < 2; ++nt) {
            #pragma unroll
            for (int reg = 0; reg < 4; ++reg) {
                const int oc = (w * 4 + mt) * 16 + q * 4 + reg;
                const int n = n0 + nt * 16 + lr;
                const size_t off = (size_t)(b * C_ + oc) * N_ + n;
                out[off] = x[off] + gm * (acc[mt][nt][reg] + o_b[oc]);
            }
        }
    }
}

// ---------------------------------------------------------------------------
extern "C" void kernel_launch(void* const* d_in, const int* in_sizes, int n_in,
                              void* d_out, int out_size, void* d_ws, size_t ws_size,
                              hipStream_t stream)
{
    const float* x       = (const float*)d_in[0];
    const float* theta_w = (const float*)d_in[1];
    const float* theta_b = (const float*)d_in[2];
    const float* phi_w   = (const float*)d_in[3];
    const float* phi_b   = (const float*)d_in[4];
    const float* g_w     = (const float*)d_in[5];
    const float* g_b     = (const float*)d_in[6];
    const float* o_w     = (const float*)d_in[7];
    const float* o_b     = (const float*)d_in[8];
    const float* gamma   = (const float*)d_in[9];
    float* out = (float*)d_out;

    // workspace: xT16 8MB | W16 96KB | ow16 64KB | theta_t 1MB | phi_t 1MB |
    //            g16 4MB | Z 64KB | o_p0 8MB | o_p1 8MB   (~31 MB)
    u16* xT16    = (u16*)d_ws;
    u16* W16     = xT16 + (size_t)B_ * N_ * C_;
    u16* ow16    = W16 + 192 * C_;
    u16* theta_t = ow16 + C_ * CV_;
    u16* phi_t   = theta_t + (size_t)B_ * N_ * CK_;
    u16* g16     = phi_t + (size_t)B_ * N_ * CK_;
    float* Z     = (float*)(g16 + (size_t)B_ * CV_ * N_);
    float* o_p0  = Z + (size_t)B_ * N_;
    float* o_p1  = o_p0 + (size_t)B_ * N_ * CV_;

    hipMemsetAsync(Z, 0, (size_t)B_ * N_ * sizeof(float), stream);

    wconv_kernel<<<dim3(320), 256, 0, stream>>>(theta_w, phi_w, g_w, o_w, W16, ow16);
    xt_kernel<<<dim3(N_ / 64, C_ / 64, B_), 256, 0, stream>>>(x, xT16);
    proj_mfma_kernel<<<dim3(N_ / 64, B_), 256, 0, stream>>>(
        xT16, W16, theta_b, phi_b, g_b, theta_t, phi_t, g16);
    colstats_kernel<<<dim3(N_ / 32, 4, B_), 256, 0, stream>>>(theta_t, phi_t, Z);
    gscale_kernel<<<dim3((B_ * CV_ * N_) / 2048), 256, 0, stream>>>(g16, Z);
    opre_kernel<<<dim3(1024), 256, 0, stream>>>(theta_t, phi_t, g16, o_p0, o_p1);
    final_mfma_kernel<<<dim3(N_ / 32, B_), 256, 0, stream>>>(
        o_p0, o_p1, ow16, o_b, gamma, x, out);
}

// Round 5
// 190.040 us; speedup vs baseline: 1.5422x; 1.5422x over previous
//
#include <hip/hip_runtime.h>
#include <math.h>

// Problem constants
#define B_  4
#define C_  256
#define N_  4096
#define CK_ 32
#define CV_ 128

typedef __attribute__((ext_vector_type(8))) short short8;  // 8 bf16 = 4 VGPRs
typedef __attribute__((ext_vector_type(4))) float f32x4;   // MFMA C/D frag
typedef unsigned short u16;
typedef unsigned int   u32;

static constexpr float LOG2E = 1.4426950408889634f;

static __device__ __forceinline__ u16 f2bf(float f) {       // fp32 -> bf16 RNE
    u32 u = __float_as_uint(f);
    u = (u + 0x7FFFu + ((u >> 16) & 1u)) >> 16;
    return (u16)u;
}
static __device__ __forceinline__ float bf2f(u16 h) {
    return __uint_as_float(((u32)h) << 16);
}

// native transcendentals
static __device__ __forceinline__ float fexp2(float x) {
#if __has_builtin(__builtin_amdgcn_exp2f)
    return __builtin_amdgcn_exp2f(x);
#else
    float r; asm("v_exp_f32 %0, %1\n\ts_nop 0" : "=v"(r) : "v"(x)); return r;
#endif
}
static __device__ __forceinline__ float frcp(float x) {
#if __has_builtin(__builtin_amdgcn_rcpf)
    return __builtin_amdgcn_rcpf(x);
#else
    float r; asm("v_rcp_f32 %0, %1\n\ts_nop 0" : "=v"(r) : "v"(x)); return r;
#endif
}
// pack two fp32 -> 2x bf16 (RNE), lo = a, hi = b
static __device__ __forceinline__ u32 cvt_pk_bf16(float a, float b) {
    u32 r; asm("v_cvt_pk_bf16_f32 %0, %1, %2" : "=v"(r) : "v"(a), "v"(b));
    return r;
}

// ---------------------------------------------------------------------------
// Kernel 0: prep = x transpose/convert  +  weight convert (merged).
// Grid (N/64 + 5, C/64, B). Blocks with x >= 64 do the weight convert:
// 5*4*4 = 80 blocks * 256 thr * 4 elem = 81920 elements.
// ---------------------------------------------------------------------------
__global__ __launch_bounds__(256) void prep_kernel(
    const float* __restrict__ x, u16* __restrict__ xT16,
    const float* __restrict__ theta_w, const float* __restrict__ phi_w,
    const float* __restrict__ g_w,     const float* __restrict__ o_w,
    u16* __restrict__ W16, u16* __restrict__ ow16)
{
    if (blockIdx.x >= N_ / 64) {
        const int base = (((blockIdx.x - N_ / 64) * 16 + blockIdx.y * 4 + blockIdx.z) * 256
                          + threadIdx.x) * 4;
        #pragma unroll
        for (int e0 = 0; e0 < 4; ++e0) {
            const int e = base + e0;
            if (e < 8192)        W16[e] = f2bf(theta_w[e] * LOG2E);
            else if (e < 16384)  W16[e] = f2bf(phi_w[e - 8192]);
            else if (e < 49152)  W16[e] = f2bf(g_w[e - 16384]);
            else                 ow16[e - 49152] = f2bf(o_w[e - 49152]);
        }
        return;
    }

    const int b = blockIdx.z, c0 = blockIdx.y * 64, n0 = blockIdx.x * 64;
    const int t = threadIdx.x;
    __shared__ float tile[64][65];

    const int cr = t >> 4, nc = (t & 15) * 4;
    #pragma unroll
    for (int it = 0; it < 4; ++it) {
        const float4 v = *(const float4*)(x + (size_t)(b * C_ + c0 + cr + it * 16) * N_ + n0 + nc);
        tile[cr + it * 16][nc + 0] = v.x; tile[cr + it * 16][nc + 1] = v.y;
        tile[cr + it * 16][nc + 2] = v.z; tile[cr + it * 16][nc + 3] = v.w;
    }
    __syncthreads();
    const int n = t >> 2, cg = (t & 3) * 16;
    union { u16 us[16]; uint4 u4[2]; } pk;
    #pragma unroll
    for (int e = 0; e < 16; ++e) pk.us[e] = f2bf(tile[cg + e][n]);
    uint4* dst = (uint4*)(xT16 + (size_t)(b * N_ + n0 + n) * C_ + c0 + cg);
    dst[0] = pk.u4[0]; dst[1] = pk.u4[1];
}

// ---------------------------------------------------------------------------
// Kernel 1: projections via MFMA. theta_t/phi_t [n][32] row-major. g stored
// UNSCALED in the PV B-fragment-tiled layout:
//   g2[((b*8 + ctile)*128 + jchunk)*512 + lane*8 + slot]
//   element (c, j): ctile=c>>4, lane=(c&15)+16*((j>>3)&3), slot=j&7,
//   jchunk=j>>5. A wave's PV B-frag load is then one contiguous 1 KB block.
// ---------------------------------------------------------------------------
__global__ __launch_bounds__(256) void proj_mfma_kernel(
    const u16* __restrict__ xT16, const u16* __restrict__ W16,
    const float* __restrict__ theta_b, const float* __restrict__ phi_b,
    const float* __restrict__ g_b,
    u16* __restrict__ theta_t, u16* __restrict__ phi_t, u16* __restrict__ g2)
{
    const int b = blockIdx.y, n0 = blockIdx.x * 64;
    const int w = threadIdx.x >> 6, lane = threadIdx.x & 63;
    const int lr = lane & 15, q = lane >> 4;
    const f32x4 zf = {0.f, 0.f, 0.f, 0.f};

    // ---- theta/phi: wave w owns pixel m-tile w ----
    const u16* xrow = xT16 + (size_t)(b * N_ + n0 + w * 16 + lr) * C_;
    f32x4 acc[4];
    #pragma unroll
    for (int nt = 0; nt < 4; ++nt) acc[nt] = zf;
    for (int ks = 0; ks < 8; ++ks) {
        const short8 aX = *(const short8*)(xrow + ks * 32 + q * 8);
        #pragma unroll
        for (int nt = 0; nt < 4; ++nt) {
            const short8 bW = *(const short8*)(W16 + (size_t)(nt * 16 + lr) * C_ + ks * 32 + q * 8);
            acc[nt] = __builtin_amdgcn_mfma_f32_16x16x32_bf16(aX, bW, acc[nt], 0, 0, 0);
        }
    }
    #pragma unroll
    for (int nt = 0; nt < 4; ++nt) {
        const int o = nt * 16 + lr;
        #pragma unroll
        for (int reg = 0; reg < 4; ++reg) {
            const int n = n0 + w * 16 + q * 4 + reg;
            if (nt < 2)
                theta_t[(size_t)(b * N_ + n) * CK_ + o] = f2bf(acc[nt][reg] + theta_b[o] * LOG2E);
            else
                phi_t[(size_t)(b * N_ + n) * CK_ + (o - 32)] = f2bf(acc[nt][reg] + phi_b[o - 32]);
        }
    }

    // ---- g: wave w owns c m-tiles {2w, 2w+1}; store in frag-tiled layout ----
    #pragma unroll
    for (int mp = 0; mp < 2; ++mp) {
        const int ctile = w * 2 + mp;
        const int crow = ctile * 16;
        f32x4 ag[4];
        #pragma unroll
        for (int nt = 0; nt < 4; ++nt) ag[nt] = zf;
        for (int ks = 0; ks < 8; ++ks) {
            const short8 aW = *(const short8*)(W16 + (size_t)(64 + crow + lr) * C_ + ks * 32 + q * 8);
            #pragma unroll
            for (int nt = 0; nt < 4; ++nt) {
                const short8 bX = *(const short8*)(xT16 + (size_t)(b * N_ + n0 + nt * 16 + lr) * C_ + ks * 32 + q * 8);
                ag[nt] = __builtin_amdgcn_mfma_f32_16x16x32_bf16(aW, bX, ag[nt], 0, 0, 0);
            }
        }
        #pragma unroll
        for (int nt = 0; nt < 4; ++nt) {
            const int jchunk = (n0 >> 5) + (nt >> 1);
            const int lhi = (nt & 1) * 2 + (lr >> 3);
            #pragma unroll
            for (int reg = 0; reg < 4; ++reg) {
                const int c = crow + q * 4 + reg;
                const int lane2 = (q * 4 + reg) + 16 * lhi;
                g2[((size_t)(b * 8 + ctile) * 128 + jchunk) * 512 + lane2 * 8 + (lr & 7)]
                    = f2bf(ag[nt][reg] + g_b[c]);
            }
        }
    }
}

// ---------------------------------------------------------------------------
// Kernel 2: Z[b][j] = sum_i exp2(S[i][j]) via MFMA.
// R1-PROVEN VERSION (reverted verbatim). Grid (N/32, 4, B).
// ---------------------------------------------------------------------------
__global__ __launch_bounds__(256) void colstats_kernel(
    const u16* __restrict__ theta_t, const u16* __restrict__ phi_t,
    float* __restrict__ Z)
{
    const int b  = blockIdx.z;
    const int j0 = blockIdx.x * 32;
    const int istart = blockIdx.y * (N_ / 4);
    const int tid = threadIdx.x;
    const int wave = tid >> 6, lane = tid & 63;
    const int lr = lane & 15, q = lane >> 4;

    const int jW = j0 + (wave & 1) * 16;
    const short8 bF = *(const short8*)(phi_t + (size_t)(b * N_ + jW + lr) * CK_ + q * 8);

    const u16* thp = theta_t + (size_t)b * N_ * CK_;
    const f32x4 zero = {0.f, 0.f, 0.f, 0.f};
    float zacc = 0.f;
    for (int it = istart + (wave >> 1) * 16; it < istart + N_ / 4; it += 32) {
        const short8 aF = *(const short8*)(thp + (size_t)(it + lr) * CK_ + q * 8);
        f32x4 S = __builtin_amdgcn_mfma_f32_16x16x32_bf16(aF, bF, zero, 0, 0, 0);
        zacc += fexp2(S[0]) + fexp2(S[1]) + fexp2(S[2]) + fexp2(S[3]);
    }
    zacc += __shfl_xor(zacc, 16);
    zacc += __shfl_xor(zacc, 32);
    if (lane < 16) atomicAdd(&Z[(size_t)b * N_ + jW + lr], zacc);
}

// ---------------------------------------------------------------------------
// Kernel 3: fold 1/Z into g2 (in place, bf16). R1-proven normalization path,
// adapted to g2's frag-tiled layout. 8 consecutive u16 = one (c-row, 8 j)
// group: j = jchunk*32 + ((lane2>>4)<<3) + slot, contiguous in j.
// idx>>19 = b (per-b block = 8*128*512 u16); (idx>>9)&127 = jchunk;
// (idx>>7)&3 = lane2>>4.
// ---------------------------------------------------------------------------
__global__ __launch_bounds__(256) void gscale_kernel(
    u16* __restrict__ g2, const float* __restrict__ Z)
{
    const size_t idx = ((size_t)blockIdx.x * 256 + threadIdx.x) * 8;
    const int b = (int)(idx >> 19);
    const int j = (int)(((idx >> 9) & 127) * 32 + ((idx >> 7) & 3) * 8);
    uint4 raw = *(const uint4*)(g2 + idx);
    const float4 z0 = *(const float4*)(Z + (size_t)b * N_ + j);
    const float4 z1 = *(const float4*)(Z + (size_t)b * N_ + j + 4);
    const float zz[8] = {z0.x, z0.y, z0.z, z0.w, z1.x, z1.y, z1.z, z1.w};
    u16* pr = (u16*)&raw;
    union { u16 us[8]; uint4 u4; } pk;
    #pragma unroll
    for (int k = 0; k < 8; ++k) pk.us[k] = f2bf(bf2f(pr[k]) * frcp(zz[k]));
    *(uint4*)(g2 + idx) = pk.u4;
}

// ---------------------------------------------------------------------------
// Kernel 4: o_pre partial. Barrier-free, LDS-free. E = exp2(S) plain
// (R2-proven pairing); normalization pre-folded into g2 by gscale.
// Per wave: IT=4 i-tiles (64 i), ct=2 c-tiles (32 c), one j-half.
// Per 32-j chunk: 2 phi gathers + 2 contiguous 1KB g2 loads feed 24 MFMAs.
// Depth-2 register prefetch (named regs, ping-pong).
// Output written in final's B-frag-tiled layout.
// ---------------------------------------------------------------------------
__global__ __launch_bounds__(256, 2) void opre_kernel(
    const u16* __restrict__ theta_t, const u16* __restrict__ phi_t,
    const u16* __restrict__ g2,
    float* __restrict__ o_p0, float* __restrict__ o_p1)
{
    const int bx = blockIdx.x;
    const int igg = bx & 15, ch = (bx >> 4) & 3, jh = (bx >> 6) & 1, b = bx >> 7;
    const int w = threadIdx.x >> 6, lane = threadIdx.x & 63;
    const int lr = lane & 15, q = lane >> 4;
    const int i0 = (igg * 4 + w) * 64;
    const f32x4 zf = {0.f, 0.f, 0.f, 0.f};

    // theta B-frags for 4 i-tiles
    short8 bT[4];
    #pragma unroll
    for (int it = 0; it < 4; ++it)
        bT[it] = *(const short8*)(theta_t + (size_t)(b * N_ + i0 + it * 16 + lr) * CK_ + q * 8);

    // phi A-frag row permutation (row r <-> j = (r>>2)*8 + (r&3))
    const int ja = (lr >> 2) * 8 + (lr & 3);
    const int jstart = jh * (N_ / 2);
    const u16* pA = phi_t + ((size_t)(b * N_) + jstart + ja) * CK_ + q * 8;
    const u16* pG = g2 + ((size_t)(b * 8 + ch * 2) * 128 + jh * 64) * 512 + lane * 8;

    f32x4 acc[4][2];
    #pragma unroll
    for (int it = 0; it < 4; ++it) { acc[it][0] = zf; acc[it][1] = zf; }

    // depth-2 prefetch (named registers, ping-pong)
    short8 A0a = *(const short8*)(pA);
    short8 A1a = *(const short8*)(pA + 4 * CK_);
    short8 G0a = *(const short8*)(pG);
    short8 G1a = *(const short8*)(pG + 128 * 512);
    short8 A0b = *(const short8*)(pA + 32 * CK_);
    short8 A1b = *(const short8*)(pA + 36 * CK_);
    short8 G0b = *(const short8*)(pG + 512);
    short8 G1b = *(const short8*)(pG + 128 * 512 + 512);

#define OPRE_CHUNK(K, A0r, A1r, G0r, G1r)                                          \
    {                                                                               \
        const short8 cA0 = A0r, cA1 = A1r, cG0 = G0r, cG1 = G1r;                    \
        f32x4 Sa[4], Sb[4];                                                         \
        _Pragma("unroll")                                                           \
        for (int it = 0; it < 4; ++it) {                                            \
            Sa[it] = __builtin_amdgcn_mfma_f32_16x16x32_bf16(cA0, bT[it], zf, 0, 0, 0); \
            Sb[it] = __builtin_amdgcn_mfma_f32_16x16x32_bf16(cA1, bT[it], zf, 0, 0, 0); \
        }                                                                           \
        const int kn = ((K) + 2) & 63;                                              \
        A0r = *(const short8*)(pA + (size_t)kn * (32 * CK_));                       \
        A1r = *(const short8*)(pA + (size_t)kn * (32 * CK_) + 4 * CK_);             \
        G0r = *(const short8*)(pG + kn * 512);                                      \
        G1r = *(const short8*)(pG + 128 * 512 + kn * 512);                          \
        _Pragma("unroll")                                                           \
        for (int it = 0; it < 4; ++it) {                                            \
            union { u32 u[4]; short8 s8; } ef;                                      \
            ef.u[0] = cvt_pk_bf16(fexp2(Sa[it][0]), fexp2(Sa[it][1]));              \
            ef.u[1] = cvt_pk_bf16(fexp2(Sa[it][2]), fexp2(Sa[it][3]));              \
            ef.u[2] = cvt_pk_bf16(fexp2(Sb[it][0]), fexp2(Sb[it][1]));              \
            ef.u[3] = cvt_pk_bf16(fexp2(Sb[it][2]), fexp2(Sb[it][3]));              \
            acc[it][0] = __builtin_amdgcn_mfma_f32_16x16x32_bf16(ef.s8, cG0, acc[it][0], 0, 0, 0); \
            acc[it][1] = __builtin_amdgcn_mfma_f32_16x16x32_bf16(ef.s8, cG1, acc[it][1], 0, 0, 0); \
        }                                                                           \
    }

    for (int k = 0; k < 64; k += 2) {
        OPRE_CHUNK(k,     A0a, A1a, G0a, G1a)
        OPRE_CHUNK(k + 1, A0b, A1b, G0b, G1b)
    }
#undef OPRE_CHUNK

    // store partials in final's B-frag-tiled layout:
    // op[(((b*256 + ntile)*4 + ks)*64 + lane')*8 + slot]
    // element (i, cv): ntile=i>>4, ks=cv>>5(=ch), lane'=(i&15)+16*((cv>>3)&3), slot=cv&7
    float* op = (jh ? o_p1 : o_p0);
    #pragma unroll
    for (int it = 0; it < 4; ++it) {
        const size_t tb = ((size_t)(b * 256 + (i0 >> 4) + it) * 4 + ch) * 512;
        #pragma unroll
        for (int ct = 0; ct < 2; ++ct) {
            #pragma unroll
            for (int reg = 0; reg < 4; ++reg) {
                const int lane2 = (q * 4 + reg) + 16 * (ct * 2 + (lr >> 3));
                op[tb + lane2 * 8 + (lr & 7)] = acc[it][ct][reg];
            }
        }
    }
}

// ---------------------------------------------------------------------------
// Kernel 5: out = x + gamma * (o_w @ (o_p0 + o_p1) + o_b) via MFMA.
// o_p frag-tiled -> bP loads are contiguous float4s.
// Grid (N/32, B) = 512 blocks, block 256 (4 waves).
// ---------------------------------------------------------------------------
__global__ __launch_bounds__(256) void final_mfma_kernel(
    const float* __restrict__ o_p0, const float* __restrict__ o_p1,
    const u16* __restrict__ ow16, const float* __restrict__ o_b,
    const float* __restrict__ gamma, const float* __restrict__ x,
    float* __restrict__ out)
{
    const int b = blockIdx.y, n0 = blockIdx.x * 32;
    const int w = threadIdx.x >> 6, lane = threadIdx.x & 63;
    const int lr = lane & 15, q = lane >> 4;
    const f32x4 zf = {0.f, 0.f, 0.f, 0.f};

    f32x4 acc[4][2];
    #pragma unroll
    for (int mt = 0; mt < 4; ++mt)
        #pragma unroll
        for (int nt = 0; nt < 2; ++nt) acc[mt][nt] = zf;

    for (int ks = 0; ks < 4; ++ks) {
        short8 bP[2];
        #pragma unroll
        for (int nt = 0; nt < 2; ++nt) {
            const size_t base = (((size_t)(b * 256 + (n0 >> 4) + nt) * 4 + ks) * 64 + lane) * 8;
            const float4 a0 = *(const float4*)(o_p0 + base);
            const float4 a1 = *(const float4*)(o_p0 + base + 4);
            const float4 c0 = *(const float4*)(o_p1 + base);
            const float4 c1 = *(const float4*)(o_p1 + base + 4);
            union { u32 u[4]; short8 s8; } pk;
            pk.u[0] = cvt_pk_bf16(a0.x + c0.x, a0.y + c0.y);
            pk.u[1] = cvt_pk_bf16(a0.z + c0.z, a0.w + c0.w);
            pk.u[2] = cvt_pk_bf16(a1.x + c1.x, a1.y + c1.y);
            pk.u[3] = cvt_pk_bf16(a1.z + c1.z, a1.w + c1.w);
            bP[nt] = pk.s8;
        }
        #pragma unroll
        for (int mt = 0; mt < 4; ++mt) {
            const short8 aW = *(const short8*)(ow16 + (size_t)((w * 4 + mt) * 16 + lr) * CV_ + ks * 32 + q * 8);
            #pragma unroll
            for (int nt = 0; nt < 2; ++nt)
                acc[mt][nt] = __builtin_amdgcn_mfma_f32_16x16x32_bf16(aW, bP[nt], acc[mt][nt], 0, 0, 0);
        }
    }

    const float gm = gamma[0];
    #pragma unroll
    for (int mt = 0; mt < 4; ++mt) {
        #pragma unroll
        for (int nt = 0; nt < 2; ++nt) {
            #pragma unroll
            for (int reg = 0; reg < 4; ++reg) {
                const int oc = (w * 4 + mt) * 16 + q * 4 + reg;
                const int n = n0 + nt * 16 + lr;
                const size_t off = (size_t)(b * C_ + oc) * N_ + n;
                out[off] = x[off] + gm * (acc[mt][nt][reg] + o_b[oc]);
            }
        }
    }
}

// ---------------------------------------------------------------------------
extern "C" void kernel_launch(void* const* d_in, const int* in_sizes, int n_in,
                              void* d_out, int out_size, void* d_ws, size_t ws_size,
                              hipStream_t stream)
{
    const float* x       = (const float*)d_in[0];
    const float* theta_w = (const float*)d_in[1];
    const float* theta_b = (const float*)d_in[2];
    const float* phi_w   = (const float*)d_in[3];
    const float* phi_b   = (const float*)d_in[4];
    const float* g_w     = (const float*)d_in[5];
    const float* g_b     = (const float*)d_in[6];
    const float* o_w     = (const float*)d_in[7];
    const float* o_b     = (const float*)d_in[8];
    const float* gamma   = (const float*)d_in[9];
    float* out = (float*)d_out;

    // workspace: xT16 8MB | W16 96KB | ow16 64KB | theta_t 1MB | phi_t 1MB |
    //            g2 4MB | Z 64KB | o_p0 8MB | o_p1 8MB   (~31 MB)
    u16* xT16    = (u16*)d_ws;
    u16* W16     = xT16 + (size_t)B_ * N_ * C_;
    u16* ow16    = W16 + 192 * C_;
    u16* theta_t = ow16 + C_ * CV_;
    u16* phi_t   = theta_t + (size_t)B_ * N_ * CK_;
    u16* g2      = phi_t + (size_t)B_ * N_ * CK_;
    float* Z     = (float*)(g2 + (size_t)B_ * CV_ * N_);
    float* o_p0  = Z + (size_t)B_ * N_;
    float* o_p1  = o_p0 + (size_t)B_ * N_ * CV_;

    hipMemsetAsync(Z, 0, (size_t)B_ * N_ * sizeof(float), stream);

    prep_kernel<<<dim3(N_ / 64 + 5, C_ / 64, B_), 256, 0, stream>>>(
        x, xT16, theta_w, phi_w, g_w, o_w, W16, ow16);
    proj_mfma_kernel<<<dim3(N_ / 64, B_), 256, 0, stream>>>(
        xT16, W16, theta_b, phi_b, g_b, theta_t, phi_t, g2);
    colstats_kernel<<<dim3(N_ / 32, 4, B_), 256, 0, stream>>>(theta_t, phi_t, Z);
    gscale_kernel<<<dim3((B_ * CV_ * N_) / 2048), 256, 0, stream>>>(g2, Z);
    opre_kernel<<<dim3(512), 256, 0, stream>>>(theta_t, phi_t, g2, o_p0, o_p1);
    final_mfma_kernel<<<dim3(N_ / 32, B_), 256, 0, stream>>>(
        o_p0, o_p1, ow16, o_b, gamma, x, out);
}